// Round 1
// baseline (12.951 us; speedup 1.0000x reference)
//
#include <hip/hip_runtime.h>

#define HIDDEN 64

// PairPot: out[i*N+j] = mask ? MLP(|min_image(xyz[j]-xyz[i])|) : 0
// mask = dis_sq < 2.5^2 && dis_sq != 0
// Fast path (b1 == 0, detected at runtime): MLP(r) = (sum_{w1k>0} w1k*w2k)*r + b2
__global__ __launch_bounds__(256) void PairPot_kernel(
    const float* __restrict__ xyz, const float* __restrict__ cell,
    const float* __restrict__ w1, const float* __restrict__ b1,
    const float* __restrict__ w2, const float* __restrict__ b2,
    float* __restrict__ out, int N)
{
    __shared__ float s_w1[HIDDEN], s_b1[HIDDEN], s_w2[HIDDEN];
    __shared__ float s_c, s_b2;
    __shared__ int s_fast;

    // Per-block precompute on wave 0 (threads 0..63): stash weights, detect
    // b1==0 fast path, and reduce c = sum_{w1k>0} w1k*w2k.
    int t = threadIdx.x;
    if (t < HIDDEN) {
        float w1k = w1[t], b1k = b1[t], w2k = w2[t];
        s_w1[t] = w1k; s_b1[t] = b1k; s_w2[t] = w2k;
        float c = (w1k > 0.0f) ? __fmul_rn(w1k, w2k) : 0.0f;
        #pragma unroll
        for (int off = 32; off; off >>= 1) c += __shfl_xor(c, off, 64);
        unsigned long long bz = __ballot(b1k == 0.0f);
        if (t == 0) { s_c = c; s_b2 = b2[0]; s_fast = (bz == ~0ULL) ? 1 : 0; }
    }
    __syncthreads();

    const int i  = blockIdx.y;                       // row (particle i)
    const int jg = blockIdx.x * 256 + threadIdx.x;   // float4 group along j
    const int n4 = N >> 2;
    if (jg >= n4) return;
    const int j0 = jg << 2;

    const float cx = cell[0], cy = cell[1], cz = cell[2];
    const float hx = __fmul_rn(0.5f, cx);
    const float hy = __fmul_rn(0.5f, cy);
    const float hz = __fmul_rn(0.5f, cz);

    const float xi0 = xyz[3*i+0], xi1 = xyz[3*i+1], xi2 = xyz[3*i+2];

    // 4 particles j0..j0+3 = 12 contiguous floats = 3 coalesced float4 loads
    const float4* pj = reinterpret_cast<const float4*>(xyz + 3*j0);
    const float4 va = pj[0], vb = pj[1], vc = pj[2];
    const float jx[4] = {va.x, va.w, vb.z, vc.y};
    const float jy[4] = {va.y, vb.x, vb.w, vc.z};
    const float jz[4] = {va.z, vb.y, vc.x, vc.w};

    const bool  fast  = (s_fast != 0);
    const float c_lin = s_c;
    const float b2v   = s_b2;

    float res[4];
    #pragma unroll
    for (int u = 0; u < 4; ++u) {
        // d = xyz[j] - xyz[i], minimum-image wrap. __f*_rn ops forbid fma
        // contraction so the mask decision matches the reference bit-wise.
        float dx = __fsub_rn(jx[u], xi0);
        float dy = __fsub_rn(jy[u], xi1);
        float dz = __fsub_rn(jz[u], xi2);
        dx = __fadd_rn(dx, (dx >= hx) ? -cx : ((dx < -hx) ? cx : 0.0f));
        dy = __fadd_rn(dy, (dy >= hy) ? -cy : ((dy < -hy) ? cy : 0.0f));
        dz = __fadd_rn(dz, (dz >= hz) ? -cz : ((dz < -hz) ? cz : 0.0f));
        float s = __fadd_rn(__fadd_rn(__fmul_rn(dx, dx), __fmul_rn(dy, dy)),
                            __fmul_rn(dz, dz));
        bool m = (s < 6.25f) && (s != 0.0f);
        float r = sqrtf(s);
        float e;
        if (fast) {
            e = fmaf(c_lin, r, b2v);        // exact: b1==0 => piecewise-linear collapses
        } else {
            e = b2v;                        // general fallback (never taken for these inputs)
            for (int k = 0; k < HIDDEN; ++k)
                e = fmaf(fmaxf(fmaf(r, s_w1[k], s_b1[k]), 0.0f), s_w2[k], e);
        }
        res[u] = m ? e : 0.0f;
    }

    float4 o;
    o.x = res[0]; o.y = res[1]; o.z = res[2]; o.w = res[3];
    reinterpret_cast<float4*>(out)[i * n4 + jg] = o;
}

extern "C" void kernel_launch(void* const* d_in, const int* in_sizes, int n_in,
                              void* d_out, int out_size, void* d_ws, size_t ws_size,
                              hipStream_t stream) {
    const float* xyz  = (const float*)d_in[0];
    const float* cell = (const float*)d_in[1];
    const float* w1   = (const float*)d_in[2];
    const float* b1   = (const float*)d_in[3];
    const float* w2   = (const float*)d_in[4];
    const float* b2   = (const float*)d_in[5];
    float* out = (float*)d_out;

    const int N = in_sizes[0] / 3;                 // 2048
    dim3 grid((N / 4 + 255) / 256, N);             // (2, 2048)
    PairPot_kernel<<<grid, 256, 0, stream>>>(xyz, cell, w1, b1, w2, b2, out, N);
}